// Round 5
// baseline (24.542 us; speedup 1.0000x reference)
//
#include <hip/hip_runtime.h>

// SPP layer: x[16,256,64,64] f32 -> out[16,5376,13,13] f32
// Levels: k=16 (1 cell), k=8 (2x2), k=4 (4x4), STRIDE=4.
// Hierarchical max: m4 (16x16 per-thread-register) -> m8 (15x15) -> m16 (13x13).
// Levels 1+2 staged in LDS in final layout, stored as float4.
// Round 5: ALL output stores non-temporal (nt) via clang ext_vector_type
// (HIP_vector_type float4 is rejected by __builtin_nontemporal_store).
// Output is write-once/never-re-read; keep it out of L2/L3 so the 67 MB
// input stays L3-resident across graph replays.

#define BS 16
#define CH 256
#define OUT_H 13
#define OUT_W 13
#define OUT_C 5376  // 256 * (1 + 4 + 16)
#define OHW (OUT_H * OUT_W)  // 169

typedef float f32x4 __attribute__((ext_vector_type(4)));

__global__ __launch_bounds__(256) void spp_kernel(const float* __restrict__ x,
                                                  float* __restrict__ out) {
    const int plane = blockIdx.x;        // b*256 + c
    const int b = plane >> 8;
    const int c = plane & 255;
    const int t = threadIdx.x;

    __shared__ float m4s[16][17];
    __shared__ float m8s[15][16];
    __shared__ alignas(16) float out0s[OHW];        // level-0, scalar store
    __shared__ alignas(16) float out1s[4 * OHW];    // 676 dwords, final layout
    __shared__ alignas(16) float out2s[16 * OHW];   // 2704 dwords, final layout

    const float* xp = x + (size_t)plane * 4096;

    // Step 1: per-thread 4x4 tile max -> m4s[a][bb].
    {
        const int a = t >> 4, bb = t & 15;
        const float* base = xp + a * 256 + bb * 4;
        f32x4 v0 = *reinterpret_cast<const f32x4*>(base);
        f32x4 v1 = *reinterpret_cast<const f32x4*>(base + 64);
        f32x4 v2 = *reinterpret_cast<const f32x4*>(base + 128);
        f32x4 v3 = *reinterpret_cast<const f32x4*>(base + 192);
        float m01 = fmaxf(fmaxf(fmaxf(v0.x, v0.y), fmaxf(v0.z, v0.w)),
                          fmaxf(fmaxf(v1.x, v1.y), fmaxf(v1.z, v1.w)));
        float m23 = fmaxf(fmaxf(fmaxf(v2.x, v2.y), fmaxf(v2.z, v2.w)),
                          fmaxf(fmaxf(v3.x, v3.y), fmaxf(v3.z, v3.w)));
        m4s[a][bb] = fmaxf(m01, m23);
    }
    __syncthreads();

    // Step 2: m8[i][j] = max of 2x2 m4 block; i,j in [0,15)
    if (t < 225) {
        int i = t / 15, j = t % 15;
        m8s[i][j] = fmaxf(fmaxf(m4s[i][j], m4s[i + 1][j]),
                          fmaxf(m4s[i][j + 1], m4s[i + 1][j + 1]));
    }
    __syncthreads();

    // Step 3: one thread per output pixel; stage all 21 values in LDS
    // in exact output layout.
    if (t < OHW) {
        const int i = t / 13, j = t % 13;
        out0s[t] = fmaxf(fmaxf(m8s[i][j], m8s[i + 2][j]),
                         fmaxf(m8s[i][j + 2], m8s[i + 2][j + 2]));
#pragma unroll
        for (int p = 0; p < 2; ++p)
#pragma unroll
            for (int q = 0; q < 2; ++q)
                out1s[(p * 2 + q) * OHW + t] = m8s[i + 2 * p][j + 2 * q];
#pragma unroll
        for (int p = 0; p < 4; ++p)
#pragma unroll
            for (int q = 0; q < 4; ++q)
                out2s[(p * 4 + q) * OHW + t] = m4s[i + p][j + q];
    }
    __syncthreads();

    // Step 4: non-temporal vectorized writeback, all 256 threads.
    float* outb = out + (size_t)b * (OUT_C * OHW);
    f32x4* o2v = reinterpret_cast<f32x4*>(outb + (size_t)(1280 + c * 16) * OHW);
    const f32x4* s2v = reinterpret_cast<const f32x4*>(out2s);
#pragma unroll
    for (int k = t; k < 4 * OHW; k += 256)   // 676 float4s
        __builtin_nontemporal_store(s2v[k], &o2v[k]);
    if (t < OHW) {
        f32x4* o1v = reinterpret_cast<f32x4*>(outb + (size_t)(256 + c * 4) * OHW);
        __builtin_nontemporal_store(reinterpret_cast<const f32x4*>(out1s)[t], &o1v[t]);
        __builtin_nontemporal_store(out0s[t], &outb[(size_t)c * OHW + t]);
    }
}

extern "C" void kernel_launch(void* const* d_in, const int* in_sizes, int n_in,
                              void* d_out, int out_size, void* d_ws, size_t ws_size,
                              hipStream_t stream) {
    const float* x = (const float*)d_in[0];
    float* out = (float*)d_out;
    spp_kernel<<<dim3(BS * CH), dim3(256), 0, stream>>>(x, out);
}